// Round 14
// baseline (182.592 us; speedup 1.0000x reference)
//
#include <hip/hip_runtime.h>

typedef __bf16 bf16;
typedef bf16 bf16x4 __attribute__((ext_vector_type(4)));
typedef bf16 bf16x8 __attribute__((ext_vector_type(8)));
typedef float f32x4 __attribute__((ext_vector_type(4)));

#define MFMA16(A, B, C) __builtin_amdgcn_mfma_f32_16x16x32_bf16(A, B, C, 0, 0, 0)
#define NEG_BIG -30000.0f

#define GLOAD_LDS16(gptr, lptr)                                                \
    __builtin_amdgcn_global_load_lds(                                          \
        (__attribute__((address_space(1))) void*)(gptr),                       \
        (__attribute__((address_space(3))) void*)(lptr), 16, 0, 0)

#define SW(r, c8) ((r) * 64 + (((((c8) >> 3) ^ ((r) & 7))) << 3))
#define SW32(r, q) ((r) * 32 + ((((q) ^ ((r) & 3))) << 3))

// ---------------------------------------------------------------------------
__global__ void mark_k(float* __restrict__ out, float val, int n) {
    int i = blockIdx.x * 256 + threadIdx.x;
    if (i < n) out[i] = val;
}

// ---------------------------------------------------------------------------
// prep_k v2: weight transposes only (x-cvt fused into gemm_qkv A-staging).
// ---------------------------------------------------------------------------
__global__ __launch_bounds__(256) void prep_k(
    const float* __restrict__ w_qkv, bf16* __restrict__ wqkvT,
    const float* __restrict__ w_out, bf16* __restrict__ woutT) {
    __shared__ float t[32][33];
    int blk = blockIdx.x;
    const float* src; bf16* dst; int R, C, bx, by;
    if (blk < 1728) {  // w_qkv: (768,2304) -> T
        src = w_qkv; dst = wqkvT; R = 768; C = 2304;
        bx = blk % 72; by = blk / 72;
    } else {           // w_out: (768,768) -> T
        blk -= 1728;
        src = w_out; dst = woutT; R = 768; C = 768;
        bx = blk % 24; by = blk / 24;
    }
    int tid = threadIdx.x, tx = tid & 31, ty = tid >> 5;
    int x0 = bx * 32, y0 = by * 32;
#pragma unroll
    for (int i = 0; i < 4; ++i) {
        int row = y0 + ty + i * 8;
        t[ty + i * 8][tx] = src[(size_t)row * C + x0 + tx];
    }
    __syncthreads();
#pragma unroll
    for (int i = 0; i < 4; ++i) {
        int outrow = x0 + ty + i * 8;
        dst[(size_t)outrow * R + y0 + tx] = (bf16)t[tx][ty + i * 8];
    }
}

// ---------------------------------------------------------------------------
// QKV GEMM v7 = v6 + FUSED x cvt: A read directly from f32 x, reg-staged
// load+cvt+ds_write at the inverse-swizzled column (SW32 reader unchanged).
// B-staging stays global_load_lds DMA. Q-scale folds 0.125*log2(e).
// ---------------------------------------------------------------------------
#define CLD 136

__global__ __launch_bounds__(256) void gemm_qkv_v7(
    const float* __restrict__ X, const bf16* __restrict__ B,
    const float* __restrict__ bias, bf16* __restrict__ Qh,
    bf16* __restrict__ Kh, bf16* __restrict__ Vth) {
    __shared__ __align__(16) bf16 SMEM[128 * CLD];
    int tid = threadIdx.x, lane = tid & 63, wave = tid >> 6;
    int quad = lane >> 4, l16 = lane & 15;
    int wr = wave >> 1, wc = wave & 1;
    int t = ((blockIdx.x & 7) * 72) + (blockIdx.x >> 3);  // bijective 576=8*72
    int bx = t % 18, by = t / 18;
    int m0 = by * 128, n0 = bx * 128;
    const int K = 768;
    const f32x4 fz = {0.f, 0.f, 0.f, 0.f};
    f32x4 acc[4][4];
#pragma unroll
    for (int nj = 0; nj < 4; ++nj)
#pragma unroll
        for (int mi = 0; mi < 4; ++mi) acc[nj][mi] = fz;
    const float* Xblk = X + (size_t)m0 * K;
    const bf16* Bblk = B + (size_t)n0 * K;
    int srow = lane >> 2, c = lane & 3;

    auto stageA = [&](int kn, int d) {
#pragma unroll
        for (int i = 0; i < 2; ++i) {
            int r0 = i * 64 + wave * 16;
            int row = r0 + srow;
            int sc = (c ^ (row & 3)) << 3;
            const float* src = &Xblk[(size_t)row * K + kn + sc];
            float4 a = *(const float4*)src;
            float4 b2 = *(const float4*)(src + 4);
            bf16x8 w;
            w[0] = (bf16)a.x;  w[1] = (bf16)a.y;
            w[2] = (bf16)a.z;  w[3] = (bf16)a.w;
            w[4] = (bf16)b2.x; w[5] = (bf16)b2.y;
            w[6] = (bf16)b2.z; w[7] = (bf16)b2.w;
            *(bf16x8*)&SMEM[d * 8192 + row * 32 + c * 8] = w;
        }
    };
    auto stageB = [&](int kn, int d) {
#pragma unroll
        for (int i = 0; i < 2; ++i) {
            int r0 = i * 64 + wave * 16;
            int row = r0 + srow;
            int sc = (c ^ (row & 3)) << 3;
            GLOAD_LDS16(&Bblk[(size_t)row * K + kn + sc],
                        &SMEM[4096 + d * 8192 + r0 * 32]);
        }
    };
    stageA(0, 0);
    stageB(0, 0);

    auto body = [&](int k0, int P) {
        __syncthreads();
        if (k0 + 32 < K) { stageA(k0 + 32, P ^ 1); stageB(k0 + 32, P ^ 1); }
        const bf16* Asp = &SMEM[P * 8192];
        const bf16* Bsp = &SMEM[4096 + P * 8192];
        bf16x8 af[4], bfv[4];
#pragma unroll
        for (int tt = 0; tt < 4; ++tt) {
            af[tt]  = *(const bf16x8*)&Asp[SW32(wr * 64 + tt * 16 + l16, quad)];
            bfv[tt] = *(const bf16x8*)&Bsp[SW32(wc * 64 + tt * 16 + l16, quad)];
        }
#pragma unroll
        for (int nj = 0; nj < 4; ++nj)
#pragma unroll
            for (int mi = 0; mi < 4; ++mi)
                acc[nj][mi] = MFMA16(bfv[nj], af[mi], acc[nj][mi]);
    };
    for (int k0 = 0; k0 < K; k0 += 64) { body(k0, 0); body(k0 + 32, 1); }

    int which = n0 / 768;
    int h0 = (n0 % 768) >> 6;
    int b = m0 >> 11, l0 = m0 & 2047;
    __syncthreads();

    if (which == 2) {
#pragma unroll
        for (int nj = 0; nj < 4; ++nj) {
            int cl0 = wc * 64 + nj * 16 + quad * 4;
            float4 bv4 = *(const float4*)&bias[n0 + cl0];
            float bv[4] = {bv4.x, bv4.y, bv4.z, bv4.w};
#pragma unroll
            for (int mi = 0; mi < 4; ++mi) {
                int xrl = wr * 64 + mi * 16 + l16;
#pragma unroll
                for (int r = 0; r < 4; ++r)
                    SMEM[(cl0 + r) * CLD + xrl] = (bf16)(acc[nj][mi][r] + bv[r]);
            }
        }
    } else {
        float s = (which == 0) ? 0.18033688f : 1.0f;  // 0.125 * log2(e)
#pragma unroll
        for (int nj = 0; nj < 4; ++nj) {
            int cl0 = wc * 64 + nj * 16 + quad * 4;
            float4 bv4 = *(const float4*)&bias[n0 + cl0];
            float bv[4] = {bv4.x, bv4.y, bv4.z, bv4.w};
#pragma unroll
            for (int mi = 0; mi < 4; ++mi) {
                int xrl = wr * 64 + mi * 16 + l16;
                bf16x4 v;
#pragma unroll
                for (int r = 0; r < 4; ++r) v[r] = (bf16)((acc[nj][mi][r] + bv[r]) * s);
                *(bf16x4*)&SMEM[xrl * CLD + cl0] = v;
            }
        }
    }
    __syncthreads();

    if (which == 2) {
#pragma unroll
        for (int i = 0; i < 8; ++i) {
            int idx = i * 256 + tid;
            int cl = idx >> 4, ch = idx & 15;
            int d = cl & 63, h = h0 + (cl >> 6);
            bf16x8 v = *(const bf16x8*)&SMEM[cl * CLD + ch * 8];
            *(bf16x8*)&Vth[((size_t)(b * 12 + h) * 64 + d) * 2048 + l0 + ch * 8] = v;
        }
    } else {
        bf16* dst = (which == 0) ? Qh : Kh;
#pragma unroll
        for (int i = 0; i < 8; ++i) {
            int idx = i * 256 + tid;
            int rr = idx >> 4, ch = idx & 15;
            int h = h0 + (ch >> 3), d0 = (ch & 7) * 8;
            bf16x8 v = *(const bf16x8*)&SMEM[rr * CLD + ch * 8];
            *(bf16x8*)&dst[((size_t)(b * 12 + h) * 2048 + l0 + rr) * 64 + d0] = v;
        }
    }
}

// ---------------------------------------------------------------------------
// Out-projection GEMM v6 with fused split-merge in A-staging (unchanged).
// ---------------------------------------------------------------------------
__global__ __launch_bounds__(256) void gemm_out_v6(
    const bf16* __restrict__ po0, const bf16* __restrict__ po1,
    const float* __restrict__ lbuf, const bf16* __restrict__ B,
    const float* __restrict__ bias, float* __restrict__ C) {
    __shared__ __align__(16) bf16 As[2][64 * 32];
    __shared__ __align__(16) bf16 Bs[2][128 * 32];
    __shared__ float inv_s[768];  // idx = h*64 + local_row
    int tid = threadIdx.x, lane = tid & 63, wave = tid >> 6;
    int quad = lane >> 4, l16 = lane & 15;
    int wr = wave >> 1, wc = wave & 1;
    int t = ((blockIdx.x & 7) * 48) + (blockIdx.x >> 3);  // bijective 384=8*48
    int bx = t % 6, by = t / 6;
    int m0 = by * 64, n0 = bx * 128;
    const int K = 768, N = 768;
    int b = m0 >> 11;

#pragma unroll
    for (int j = 0; j < 3; ++j) {
        int idx = j * 256 + tid;     // 0..767
        int r = idx & 63, h = idx >> 6;
        int qrow = (m0 + r) & 2047;
        int bh = b * 12 + h;
        float l0 = lbuf[(size_t)bh * 2048 + qrow];
        float l1 = lbuf[(size_t)(24 + bh) * 2048 + qrow];
        inv_s[idx] = 1.0f / (l0 + l1);
    }
    __syncthreads();

    const f32x4 fz = {0.f, 0.f, 0.f, 0.f};
    f32x4 acc[2][4];
#pragma unroll
    for (int mi = 0; mi < 2; ++mi)
#pragma unroll
        for (int nj = 0; nj < 4; ++nj) acc[mi][nj] = fz;
    const bf16* Bblk = B + (size_t)n0 * K;
    int srow = lane >> 2, c = lane & 3;

    auto stageA = [&](int kn, int d) {
        int row = wave * 16 + srow;            // 0..63
        int sc = (c ^ (row & 3)) << 3;
        int col = kn + sc;                     // 8-span stays in one head
        float inv = inv_s[(col >> 6) * 64 + row];
        size_t gi = (size_t)(m0 + row) * 768 + col;
        bf16x8 a0 = *(const bf16x8*)&po0[gi];
        bf16x8 a1 = *(const bf16x8*)&po1[gi];
        bf16x8 w;
#pragma unroll
        for (int k = 0; k < 8; ++k)
            w[k] = (bf16)(((float)a0[k] + (float)a1[k]) * inv);
        *(bf16x8*)&As[d][row * 32 + c * 8] = w;
    };
    auto stageB = [&](int kn, int d) {
#pragma unroll
        for (int i = 0; i < 2; ++i) {
            int r0 = i * 64 + wave * 16;
            int row = r0 + srow;
            int sc = (c ^ (row & 3)) << 3;
            GLOAD_LDS16(&Bblk[(size_t)row * K + kn + sc], &Bs[d][r0 * 32]);
        }
    };
    stageA(0, 0);
    stageB(0, 0);

    auto body = [&](int k0, int P) {
        __syncthreads();
        if (k0 + 32 < K) { stageA(k0 + 32, P ^ 1); stageB(k0 + 32, P ^ 1); }
        bf16x8 af[2], bfv[4];
#pragma unroll
        for (int tt = 0; tt < 2; ++tt)
            af[tt] = *(const bf16x8*)&As[P][SW32(wr * 32 + tt * 16 + l16, quad)];
#pragma unroll
        for (int tt = 0; tt < 4; ++tt)
            bfv[tt] = *(const bf16x8*)&Bs[P][SW32(wc * 64 + tt * 16 + l16, quad)];
#pragma unroll
        for (int mi = 0; mi < 2; ++mi)
#pragma unroll
            for (int nj = 0; nj < 4; ++nj)
                acc[mi][nj] = MFMA16(af[mi], bfv[nj], acc[mi][nj]);
    };
    for (int k0 = 0; k0 < K; k0 += 64) { body(k0, 0); body(k0 + 32, 1); }

#pragma unroll
    for (int nj = 0; nj < 4; ++nj) {
        int col = n0 + wc * 64 + nj * 16 + l16;
        float bv = bias[col];
#pragma unroll
        for (int mi = 0; mi < 2; ++mi)
#pragma unroll
            for (int r = 0; r < 4; ++r) {
                int row = m0 + wr * 32 + mi * 16 + quad * 4 + r;
                C[(size_t)row * N + col] = acc[mi][nj][r] + bv;
            }
    }
}

// ---------------------------------------------------------------------------
// Flash attention v11 (round-5 best, VGPR 108) — unchanged.
// ---------------------------------------------------------------------------
__global__ __launch_bounds__(256) void flash_attn(
    const bf16* __restrict__ Q, const bf16* __restrict__ K,
    const bf16* __restrict__ V, const int* __restrict__ mask,
    bf16* __restrict__ po0, bf16* __restrict__ po1, float* __restrict__ lbuf) {
    __shared__ __align__(16) bf16 Ks[2][64 * 64];
    __shared__ __align__(16) bf16 Vs[2][64 * 64];
    __shared__ float maskS[1024];
    __shared__ int cleanF;

    int tid = threadIdx.x, lane = tid & 63, wave = tid >> 6;
    int quad = lane >> 4, l16 = lane & 15;

    int n = blockIdx.x;                  // 0..767
    int xcd = n & 7, idx = n >> 3;       // 96 blocks per XCD
    int g = xcd * 6 + (idx >> 4);        // 48 K/V panel groups
    int m = idx & 15;                    // 16 q-blocks per panel
    int bh = g % 24;
    int split = g / 24;
    int b = bh / 12;
    int s0 = split * 1024;
    int q0 = m * 128 + wave * 32;

    bf16x8 aq[2][2];
#pragma unroll
    for (int qt = 0; qt < 2; ++qt) {
        const bf16* Qp = Q + ((size_t)bh * 2048 + q0 + qt * 16 + l16) * 64;
        aq[qt][0] = *(const bf16x8*)(Qp + quad * 8);
        aq[qt][1] = *(const bf16x8*)(Qp + 32 + quad * 8);
    }

    if (tid == 0) cleanF = 1;
    __syncthreads();
    const int* mrow = mask + b * 2048 + s0;
    int myclean = 1;
#pragma unroll
    for (int i = 0; i < 4; ++i) {
        int idx2 = i * 256 + tid;
        int mv = mrow[idx2];
        maskS[idx2] = mv ? 0.0f : NEG_BIG;
        myclean &= (mv != 0);
    }
    if (!myclean) cleanF = 0;

    const f32x4 fz = {0.f, 0.f, 0.f, 0.f};
    f32x4 o[2][4];
    float l_i[2] = {0.f, 0.f};
#pragma unroll
    for (int qt = 0; qt < 2; ++qt)
#pragma unroll
        for (int dt = 0; dt < 4; ++dt) o[qt][dt] = fz;

    int srow = tid >> 3;
    int sc8  = (tid & 7) * 8;
    const bf16* Kbase = K + ((size_t)bh * 2048 + s0) * 64;
    const bf16* Vbase = V + (size_t)bh * 64 * 2048 + s0;

#pragma unroll
    for (int i = 0; i < 2; ++i) {
        int row = srow + i * 32;
        *(bf16x8*)&Ks[0][SW(row, sc8)] =
            *(const bf16x8*)&Kbase[(size_t)row * 64 + sc8];
        *(bf16x8*)&Vs[0][SW(row, sc8)] =
            *(const bf16x8*)&Vbase[(size_t)row * 2048 + sc8];
    }
    __syncthreads();
    int clean = cleanF;

    int p = 0;
    for (int kb = 0; kb < 1024; kb += 64) {
        // T14 issue-early: next-tile global loads into registers, no wait
        bf16x8 kreg[2], vreg[2];
        const int pref = (kb + 64 < 1024);
        if (pref) {
            int nb = kb + 64;
#pragma unroll
            for (int i = 0; i < 2; ++i) {
                int row = srow + i * 32;
                kreg[i] = *(const bf16x8*)&Kbase[(size_t)(nb + row) * 64 + sc8];
                vreg[i] = *(const bf16x8*)&Vbase[(size_t)row * 2048 + nb + sc8];
            }
        }

        f32x4 s[2][4];
#pragma unroll
        for (int ct = 0; ct < 4; ++ct) {
            int krow = ct * 16 + l16;
            bf16x8 kf0 = *(const bf16x8*)&Ks[p][SW(krow, quad * 8)];
            bf16x8 kf1 = *(const bf16x8*)&Ks[p][SW(krow, 32 + quad * 8)];
#pragma unroll
            for (int qt = 0; qt < 2; ++qt) {
                f32x4 t = fz;
                t = MFMA16(kf0, aq[qt][0], t);
                t = MFMA16(kf1, aq[qt][1], t);
                s[qt][ct] = t;
            }
        }

        if (!clean) {
#pragma unroll
            for (int ct = 0; ct < 4; ++ct) {
                float4 mv = *(const float4*)&maskS[kb + ct * 16 + quad * 4];
                float ma[4] = {mv.x, mv.y, mv.z, mv.w};
#pragma unroll
                for (int qt = 0; qt < 2; ++qt)
#pragma unroll
                    for (int r = 0; r < 4; ++r) s[qt][ct][r] += ma[r];
            }
        }

        // V fragments (independent of softmax; compiler overlaps)
        bf16x8 vf[2][4];
#pragma unroll
        for (int ks = 0; ks < 2; ++ks)
#pragma unroll
            for (int dt = 0; dt < 4; ++dt)
                vf[ks][dt] = *(const bf16x8*)&Vs[p][SW(dt * 16 + l16, ks * 32 + quad * 8)];

#pragma unroll
        for (int qt = 0; qt < 2; ++qt) {
            // p = exp2(s); per-lane partial l with explicit add tree
#pragma unroll
            for (int ct = 0; ct < 4; ++ct)
#pragma unroll
                for (int r = 0; r < 4; ++r)
                    s[qt][ct][r] = __builtin_amdgcn_exp2f(s[qt][ct][r]);
            float t0 = (s[qt][0][0] + s[qt][0][1]) + (s[qt][0][2] + s[qt][0][3]);
            float t1 = (s[qt][1][0] + s[qt][1][1]) + (s[qt][1][2] + s[qt][1][3]);
            float t2 = (s[qt][2][0] + s[qt][2][1]) + (s[qt][2][2] + s[qt][2][3]);
            float t3 = (s[qt][3][0] + s[qt][3][1]) + (s[qt][3][2] + s[qt][3][3]);
            l_i[qt] += (t0 + t1) + (t2 + t3);

            // pack to bf16 pairs: pk0[ct] = (r0,r1), pk1[ct] = (r2,r3)
            unsigned pk0[4], pk1[4];
#pragma unroll
            for (int ct = 0; ct < 4; ++ct) {
                asm("v_cvt_pk_bf16_f32 %0, %1, %2"
                    : "=v"(pk0[ct]) : "v"(s[qt][ct][0]), "v"(s[qt][ct][1]));
                asm("v_cvt_pk_bf16_f32 %0, %1, %2"
                    : "=v"(pk1[ct]) : "v"(s[qt][ct][2]), "v"(s[qt][ct][3]));
            }

#pragma unroll
            for (int ks = 0; ks < 2; ++ks) {
                unsigned a0 = pk0[2 * ks], c0 = pk0[2 * ks + 1];
                unsigned b0 = pk1[2 * ks], d0 = pk1[2 * ks + 1];
                asm("v_permlane32_swap_b32 %0, %1" : "+v"(a0), "+v"(c0));
                asm("v_permlane16_swap_b32 %0, %1" : "+v"(a0), "+v"(c0));
                asm("v_permlane32_swap_b32 %0, %1" : "+v"(b0), "+v"(d0));
                asm("v_permlane16_swap_b32 %0, %1" : "+v"(b0), "+v"(d0));
                union { unsigned u[4]; bf16x8 v; } ap;
                ap.u[0] = a0;  // j0,j1
                ap.u[1] = b0;  // j2,j3
                ap.u[2] = c0;  // j4,j5
                ap.u[3] = d0;  // j6,j7
#pragma unroll
                for (int dt = 0; dt < 4; ++dt)
                    o[qt][dt] = MFMA16(ap.v, vf[ks][dt], o[qt][dt]);
            }
        }

        // T14 write-late: staged tile -> other LDS buffer after compute
        if (pref) {
#pragma unroll
            for (int i = 0; i < 2; ++i) {
                int row = srow + i * 32;
                *(bf16x8*)&Ks[1 - p][SW(row, sc8)] = kreg[i];
                *(bf16x8*)&Vs[1 - p][SW(row, sc8)] = vreg[i];
            }
        }
        __syncthreads();
        p ^= 1;
    }

    // epilogue: cross-quad l reduce (out of the loop), then stores
    int h = bh % 12;
    bf16* obase = split ? po1 : po0;
#pragma unroll
    for (int qt = 0; qt < 2; ++qt) {
        l_i[qt] += __shfl_xor(l_i[qt], 16);
        l_i[qt] += __shfl_xor(l_i[qt], 32);
#pragma unroll
        for (int dt = 0; dt < 4; ++dt)
#pragma unroll
            for (int r = 0; r < 4; ++r) {
                int qrow = q0 + qt * 16 + quad * 4 + r;
                obase[((size_t)b * 2048 + qrow) * 768 + h * 64 + dt * 16 + l16] =
                    (bf16)o[qt][dt][r];
            }
        if (quad == 0) {
            int qrow = q0 + qt * 16 + l16;
            lbuf[((size_t)split * 24 + bh) * 2048 + qrow] = l_i[qt];
        }
    }
}

// ---------------------------------------------------------------------------
extern "C" void kernel_launch(void* const* d_in, const int* in_sizes, int n_in,
                              void* d_out, int out_size, void* d_ws, size_t ws_size,
                              hipStream_t stream) {
    float* out = (float*)d_out;

    const float* x = nullptr; const int* mask = nullptr;
    const float* w_qkv = nullptr; const float* b_qkv = nullptr;
    const float* w_out = nullptr; const float* b_out = nullptr;
    int found = 0;
    for (int i = 0; i < n_in; ++i) {
        switch (in_sizes[i]) {
            case 3145728: x     = (const float*)d_in[i]; found |= 1;  break;
            case 4096:    mask  = (const int*)  d_in[i]; found |= 2;  break;
            case 1769472: w_qkv = (const float*)d_in[i]; found |= 4;  break;
            case 2304:    b_qkv = (const float*)d_in[i]; found |= 8;  break;
            case 589824:  w_out = (const float*)d_in[i]; found |= 16; break;
            case 768:     b_out = (const float*)d_in[i]; found |= 32; break;
        }
    }
    if (found != 63) {
        mark_k<<<(out_size + 255) / 256, 256, 0, stream>>>(
            out, 200.0f + (float)found, out_size);
        return;
    }

    const int M = 4096, D = 768, N3 = 2304;
    const size_t HEADS_ELEMS = (size_t)24 * 2048 * 64;

    bf16* ws    = (bf16*)d_ws;
    bf16* Kh    = ws;
    bf16* Vth   = Kh + HEADS_ELEMS;
    bf16* po0   = Vth + HEADS_ELEMS;            // split-0 partial
    bf16* wqkvT = po0 + (size_t)M * D;
    bf16* woutT = wqkvT + (size_t)N3 * D;
    bf16* po1   = woutT + (size_t)D * D;        // split-1 partial
    bf16* Qh    = (bf16*)d_out;
    float* lbuf = (float*)wqkvT;                // dead after QKV (393 KB)

    prep_k<<<dim3(1728 + 576), 256, 0, stream>>>(
        w_qkv, wqkvT, w_out, woutT);

    gemm_qkv_v7<<<dim3(576), 256, 0, stream>>>(
        x, wqkvT, b_qkv, Qh, Kh, Vth);

    flash_attn<<<dim3(768), 256, 0, stream>>>(
        Qh, Kh, Vth, mask, po0, po1, lbuf);

    gemm_out_v6<<<dim3(384), 256, 0, stream>>>(
        po0, po1, lbuf, woutT, b_out, out);
}

// Round 15
// 169.479 us; speedup vs baseline: 1.0774x; 1.0774x over previous
//
#include <hip/hip_runtime.h>

typedef __bf16 bf16;
typedef bf16 bf16x4 __attribute__((ext_vector_type(4)));
typedef bf16 bf16x8 __attribute__((ext_vector_type(8)));
typedef float f32x4 __attribute__((ext_vector_type(4)));

#define MFMA16(A, B, C) __builtin_amdgcn_mfma_f32_16x16x32_bf16(A, B, C, 0, 0, 0)
#define NEG_BIG -30000.0f

#define GLOAD_LDS16(gptr, lptr)                                                \
    __builtin_amdgcn_global_load_lds(                                          \
        (__attribute__((address_space(1))) void*)(gptr),                       \
        (__attribute__((address_space(3))) void*)(lptr), 16, 0, 0)

#define SW(r, c8) ((r) * 64 + (((((c8) >> 3) ^ ((r) & 7))) << 3))
#define SW32(r, q) ((r) * 32 + ((((q) ^ ((r) & 3))) << 3))

// ---------------------------------------------------------------------------
__global__ void mark_k(float* __restrict__ out, float val, int n) {
    int i = blockIdx.x * 256 + threadIdx.x;
    if (i < n) out[i] = val;
}

// ---------------------------------------------------------------------------
// prep_k: fused {x f32->bf16 cvt} + {w_qkv transpose} + {w_out transpose}.
// (Round-14 lesson: folding the x-cvt INTO gemm_qkv's A-stage regresses —
// reg-staged ds_write has ~8-way bank conflicts (1.94M) and f32 A doubles
// FETCH; the separate cvt pass + bf16 DMA staging is strictly better.)
// ---------------------------------------------------------------------------
__global__ __launch_bounds__(256) void prep_k(
    const float* __restrict__ x, bf16* __restrict__ xb,
    const float* __restrict__ w_qkv, bf16* __restrict__ wqkvT,
    const float* __restrict__ w_out, bf16* __restrict__ woutT) {
    __shared__ float t[32][33];
    int blk = blockIdx.x;
    if (blk < 1536) {  // cvt_x segment: 1536 blocks x 2048 elems
        int i = (blk * 256 + threadIdx.x) * 8;
        float4 a = *(const float4*)&x[i];
        float4 b = *(const float4*)&x[i + 4];
        bf16x8 w;
        w[0] = (bf16)a.x; w[1] = (bf16)a.y; w[2] = (bf16)a.z; w[3] = (bf16)a.w;
        w[4] = (bf16)b.x; w[5] = (bf16)b.y; w[6] = (bf16)b.z; w[7] = (bf16)b.w;
        *(bf16x8*)&xb[i] = w;
        return;
    }
    blk -= 1536;
    const float* src; bf16* dst; int R, C, bx, by;
    if (blk < 1728) {  // w_qkv: (768,2304) -> T
        src = w_qkv; dst = wqkvT; R = 768; C = 2304;
        bx = blk % 72; by = blk / 72;
    } else {           // w_out: (768,768) -> T
        blk -= 1728;
        src = w_out; dst = woutT; R = 768; C = 768;
        bx = blk % 24; by = blk / 24;
    }
    int tid = threadIdx.x, tx = tid & 31, ty = tid >> 5;
    int x0 = bx * 32, y0 = by * 32;
#pragma unroll
    for (int i = 0; i < 4; ++i) {
        int row = y0 + ty + i * 8;
        t[ty + i * 8][tx] = src[(size_t)row * C + x0 + tx];
    }
    __syncthreads();
#pragma unroll
    for (int i = 0; i < 4; ++i) {
        int outrow = x0 + ty + i * 8;
        dst[(size_t)outrow * R + y0 + tx] = (bf16)t[tx][ty + i * 8];
    }
}

// ---------------------------------------------------------------------------
// QKV GEMM v6: unroll-by-2 literal ping-pong + XCD swizzle, bf16 A via DMA.
// Q-scale folds 0.125*log2(e) so attention uses exp2 directly.
// ---------------------------------------------------------------------------
#define CLD 136

__global__ __launch_bounds__(256) void gemm_qkv_v6(
    const bf16* __restrict__ A, const bf16* __restrict__ B,
    const float* __restrict__ bias, bf16* __restrict__ Qh,
    bf16* __restrict__ Kh, bf16* __restrict__ Vth) {
    __shared__ __align__(16) bf16 SMEM[128 * CLD];
    int tid = threadIdx.x, lane = tid & 63, wave = tid >> 6;
    int quad = lane >> 4, l16 = lane & 15;
    int wr = wave >> 1, wc = wave & 1;
    int t = ((blockIdx.x & 7) * 72) + (blockIdx.x >> 3);  // bijective 576=8*72
    int bx = t % 18, by = t / 18;
    int m0 = by * 128, n0 = bx * 128;
    const int K = 768;
    const f32x4 fz = {0.f, 0.f, 0.f, 0.f};
    f32x4 acc[4][4];
#pragma unroll
    for (int nj = 0; nj < 4; ++nj)
#pragma unroll
        for (int mi = 0; mi < 4; ++mi) acc[nj][mi] = fz;
    const bf16* Ablk = A + (size_t)m0 * K;
    const bf16* Bblk = B + (size_t)n0 * K;
    int srow = lane >> 2, c = lane & 3;

    auto stage = [&](int kn, int d) {
#pragma unroll
        for (int i = 0; i < 2; ++i) {
            int r0 = i * 64 + wave * 16;
            int row = r0 + srow;
            int sc = (c ^ (row & 3)) << 3;
            GLOAD_LDS16(&Ablk[(size_t)row * K + kn + sc],
                        &SMEM[d * 8192 + r0 * 32]);
            GLOAD_LDS16(&Bblk[(size_t)row * K + kn + sc],
                        &SMEM[4096 + d * 8192 + r0 * 32]);
        }
    };
    stage(0, 0);

    auto body = [&](int k0, int P) {
        __syncthreads();
        if (k0 + 32 < K) stage(k0 + 32, P ^ 1);
        const bf16* Asp = &SMEM[P * 8192];
        const bf16* Bsp = &SMEM[4096 + P * 8192];
        bf16x8 af[4], bfv[4];
#pragma unroll
        for (int tt = 0; tt < 4; ++tt) {
            af[tt]  = *(const bf16x8*)&Asp[SW32(wr * 64 + tt * 16 + l16, quad)];
            bfv[tt] = *(const bf16x8*)&Bsp[SW32(wc * 64 + tt * 16 + l16, quad)];
        }
#pragma unroll
        for (int nj = 0; nj < 4; ++nj)
#pragma unroll
            for (int mi = 0; mi < 4; ++mi)
                acc[nj][mi] = MFMA16(bfv[nj], af[mi], acc[nj][mi]);
    };
    for (int k0 = 0; k0 < K; k0 += 64) { body(k0, 0); body(k0 + 32, 1); }

    int which = n0 / 768;
    int h0 = (n0 % 768) >> 6;
    int b = m0 >> 11, l0 = m0 & 2047;
    __syncthreads();

    if (which == 2) {
#pragma unroll
        for (int nj = 0; nj < 4; ++nj) {
            int cl0 = wc * 64 + nj * 16 + quad * 4;
            float4 bv4 = *(const float4*)&bias[n0 + cl0];
            float bv[4] = {bv4.x, bv4.y, bv4.z, bv4.w};
#pragma unroll
            for (int mi = 0; mi < 4; ++mi) {
                int xrl = wr * 64 + mi * 16 + l16;
#pragma unroll
                for (int r = 0; r < 4; ++r)
                    SMEM[(cl0 + r) * CLD + xrl] = (bf16)(acc[nj][mi][r] + bv[r]);
            }
        }
    } else {
        float s = (which == 0) ? 0.18033688f : 1.0f;  // 0.125 * log2(e)
#pragma unroll
        for (int nj = 0; nj < 4; ++nj) {
            int cl0 = wc * 64 + nj * 16 + quad * 4;
            float4 bv4 = *(const float4*)&bias[n0 + cl0];
            float bv[4] = {bv4.x, bv4.y, bv4.z, bv4.w};
#pragma unroll
            for (int mi = 0; mi < 4; ++mi) {
                int xrl = wr * 64 + mi * 16 + l16;
                bf16x4 v;
#pragma unroll
                for (int r = 0; r < 4; ++r) v[r] = (bf16)((acc[nj][mi][r] + bv[r]) * s);
                *(bf16x4*)&SMEM[xrl * CLD + cl0] = v;
            }
        }
    }
    __syncthreads();

    if (which == 2) {
#pragma unroll
        for (int i = 0; i < 8; ++i) {
            int idx = i * 256 + tid;
            int cl = idx >> 4, ch = idx & 15;
            int d = cl & 63, h = h0 + (cl >> 6);
            bf16x8 v = *(const bf16x8*)&SMEM[cl * CLD + ch * 8];
            *(bf16x8*)&Vth[((size_t)(b * 12 + h) * 64 + d) * 2048 + l0 + ch * 8] = v;
        }
    } else {
        bf16* dst = (which == 0) ? Qh : Kh;
#pragma unroll
        for (int i = 0; i < 8; ++i) {
            int idx = i * 256 + tid;
            int rr = idx >> 4, ch = idx & 15;
            int h = h0 + (ch >> 3), d0 = (ch & 7) * 8;
            bf16x8 v = *(const bf16x8*)&SMEM[rr * CLD + ch * 8];
            *(bf16x8*)&dst[((size_t)(b * 12 + h) * 2048 + l0 + rr) * 64 + d0] = v;
        }
    }
}

// ---------------------------------------------------------------------------
// Out-projection GEMM v6 with fused split-merge in A-staging.
// ---------------------------------------------------------------------------
__global__ __launch_bounds__(256) void gemm_out_v6(
    const bf16* __restrict__ po0, const bf16* __restrict__ po1,
    const float* __restrict__ lbuf, const bf16* __restrict__ B,
    const float* __restrict__ bias, float* __restrict__ C) {
    __shared__ __align__(16) bf16 As[2][64 * 32];
    __shared__ __align__(16) bf16 Bs[2][128 * 32];
    __shared__ float inv_s[768];  // idx = h*64 + local_row
    int tid = threadIdx.x, lane = tid & 63, wave = tid >> 6;
    int quad = lane >> 4, l16 = lane & 15;
    int wr = wave >> 1, wc = wave & 1;
    int t = ((blockIdx.x & 7) * 48) + (blockIdx.x >> 3);  // bijective 384=8*48
    int bx = t % 6, by = t / 6;
    int m0 = by * 64, n0 = bx * 128;
    const int K = 768, N = 768;
    int b = m0 >> 11;

#pragma unroll
    for (int j = 0; j < 3; ++j) {
        int idx = j * 256 + tid;     // 0..767
        int r = idx & 63, h = idx >> 6;
        int qrow = (m0 + r) & 2047;
        int bh = b * 12 + h;
        float l0 = lbuf[(size_t)bh * 2048 + qrow];
        float l1 = lbuf[(size_t)(24 + bh) * 2048 + qrow];
        inv_s[idx] = 1.0f / (l0 + l1);
    }
    __syncthreads();

    const f32x4 fz = {0.f, 0.f, 0.f, 0.f};
    f32x4 acc[2][4];
#pragma unroll
    for (int mi = 0; mi < 2; ++mi)
#pragma unroll
        for (int nj = 0; nj < 4; ++nj) acc[mi][nj] = fz;
    const bf16* Bblk = B + (size_t)n0 * K;
    int srow = lane >> 2, c = lane & 3;

    auto stageA = [&](int kn, int d) {
        int row = wave * 16 + srow;            // 0..63
        int sc = (c ^ (row & 3)) << 3;
        int col = kn + sc;                     // 8-span stays in one head
        float inv = inv_s[(col >> 6) * 64 + row];
        size_t gi = (size_t)(m0 + row) * 768 + col;
        bf16x8 a0 = *(const bf16x8*)&po0[gi];
        bf16x8 a1 = *(const bf16x8*)&po1[gi];
        bf16x8 w;
#pragma unroll
        for (int k = 0; k < 8; ++k)
            w[k] = (bf16)(((float)a0[k] + (float)a1[k]) * inv);
        *(bf16x8*)&As[d][row * 32 + c * 8] = w;
    };
    auto stageB = [&](int kn, int d) {
#pragma unroll
        for (int i = 0; i < 2; ++i) {
            int r0 = i * 64 + wave * 16;
            int row = r0 + srow;
            int sc = (c ^ (row & 3)) << 3;
            GLOAD_LDS16(&Bblk[(size_t)row * K + kn + sc], &Bs[d][r0 * 32]);
        }
    };
    stageA(0, 0);
    stageB(0, 0);

    auto body = [&](int k0, int P) {
        __syncthreads();
        if (k0 + 32 < K) { stageA(k0 + 32, P ^ 1); stageB(k0 + 32, P ^ 1); }
        bf16x8 af[2], bfv[4];
#pragma unroll
        for (int tt = 0; tt < 2; ++tt)
            af[tt] = *(const bf16x8*)&As[P][SW32(wr * 32 + tt * 16 + l16, quad)];
#pragma unroll
        for (int tt = 0; tt < 4; ++tt)
            bfv[tt] = *(const bf16x8*)&Bs[P][SW32(wc * 64 + tt * 16 + l16, quad)];
#pragma unroll
        for (int mi = 0; mi < 2; ++mi)
#pragma unroll
            for (int nj = 0; nj < 4; ++nj)
                acc[mi][nj] = MFMA16(af[mi], bfv[nj], acc[mi][nj]);
    };
    for (int k0 = 0; k0 < K; k0 += 64) { body(k0, 0); body(k0 + 32, 1); }

#pragma unroll
    for (int nj = 0; nj < 4; ++nj) {
        int col = n0 + wc * 64 + nj * 16 + l16;
        float bv = bias[col];
#pragma unroll
        for (int mi = 0; mi < 2; ++mi)
#pragma unroll
            for (int r = 0; r < 4; ++r) {
                int row = m0 + wr * 32 + mi * 16 + quad * 4 + r;
                C[(size_t)row * N + col] = acc[mi][nj][r] + bv;
            }
    }
}

// ---------------------------------------------------------------------------
// Flash attention v11 (round-5 best, VGPR 108) — unchanged.
// ---------------------------------------------------------------------------
__global__ __launch_bounds__(256) void flash_attn(
    const bf16* __restrict__ Q, const bf16* __restrict__ K,
    const bf16* __restrict__ V, const int* __restrict__ mask,
    bf16* __restrict__ po0, bf16* __restrict__ po1, float* __restrict__ lbuf) {
    __shared__ __align__(16) bf16 Ks[2][64 * 64];
    __shared__ __align__(16) bf16 Vs[2][64 * 64];
    __shared__ float maskS[1024];
    __shared__ int cleanF;

    int tid = threadIdx.x, lane = tid & 63, wave = tid >> 6;
    int quad = lane >> 4, l16 = lane & 15;

    int n = blockIdx.x;                  // 0..767
    int xcd = n & 7, idx = n >> 3;       // 96 blocks per XCD
    int g = xcd * 6 + (idx >> 4);        // 48 K/V panel groups
    int m = idx & 15;                    // 16 q-blocks per panel
    int bh = g % 24;
    int split = g / 24;
    int b = bh / 12;
    int s0 = split * 1024;
    int q0 = m * 128 + wave * 32;

    bf16x8 aq[2][2];
#pragma unroll
    for (int qt = 0; qt < 2; ++qt) {
        const bf16* Qp = Q + ((size_t)bh * 2048 + q0 + qt * 16 + l16) * 64;
        aq[qt][0] = *(const bf16x8*)(Qp + quad * 8);
        aq[qt][1] = *(const bf16x8*)(Qp + 32 + quad * 8);
    }

    if (tid == 0) cleanF = 1;
    __syncthreads();
    const int* mrow = mask + b * 2048 + s0;
    int myclean = 1;
#pragma unroll
    for (int i = 0; i < 4; ++i) {
        int idx2 = i * 256 + tid;
        int mv = mrow[idx2];
        maskS[idx2] = mv ? 0.0f : NEG_BIG;
        myclean &= (mv != 0);
    }
    if (!myclean) cleanF = 0;

    const f32x4 fz = {0.f, 0.f, 0.f, 0.f};
    f32x4 o[2][4];
    float l_i[2] = {0.f, 0.f};
#pragma unroll
    for (int qt = 0; qt < 2; ++qt)
#pragma unroll
        for (int dt = 0; dt < 4; ++dt) o[qt][dt] = fz;

    int srow = tid >> 3;
    int sc8  = (tid & 7) * 8;
    const bf16* Kbase = K + ((size_t)bh * 2048 + s0) * 64;
    const bf16* Vbase = V + (size_t)bh * 64 * 2048 + s0;

#pragma unroll
    for (int i = 0; i < 2; ++i) {
        int row = srow + i * 32;
        *(bf16x8*)&Ks[0][SW(row, sc8)] =
            *(const bf16x8*)&Kbase[(size_t)row * 64 + sc8];
        *(bf16x8*)&Vs[0][SW(row, sc8)] =
            *(const bf16x8*)&Vbase[(size_t)row * 2048 + sc8];
    }
    __syncthreads();
    int clean = cleanF;

    int p = 0;
    for (int kb = 0; kb < 1024; kb += 64) {
        // T14 issue-early: next-tile global loads into registers, no wait
        bf16x8 kreg[2], vreg[2];
        const int pref = (kb + 64 < 1024);
        if (pref) {
            int nb = kb + 64;
#pragma unroll
            for (int i = 0; i < 2; ++i) {
                int row = srow + i * 32;
                kreg[i] = *(const bf16x8*)&Kbase[(size_t)(nb + row) * 64 + sc8];
                vreg[i] = *(const bf16x8*)&Vbase[(size_t)row * 2048 + nb + sc8];
            }
        }

        f32x4 s[2][4];
#pragma unroll
        for (int ct = 0; ct < 4; ++ct) {
            int krow = ct * 16 + l16;
            bf16x8 kf0 = *(const bf16x8*)&Ks[p][SW(krow, quad * 8)];
            bf16x8 kf1 = *(const bf16x8*)&Ks[p][SW(krow, 32 + quad * 8)];
#pragma unroll
            for (int qt = 0; qt < 2; ++qt) {
                f32x4 t = fz;
                t = MFMA16(kf0, aq[qt][0], t);
                t = MFMA16(kf1, aq[qt][1], t);
                s[qt][ct] = t;
            }
        }

        if (!clean) {
#pragma unroll
            for (int ct = 0; ct < 4; ++ct) {
                float4 mv = *(const float4*)&maskS[kb + ct * 16 + quad * 4];
                float ma[4] = {mv.x, mv.y, mv.z, mv.w};
#pragma unroll
                for (int qt = 0; qt < 2; ++qt)
#pragma unroll
                    for (int r = 0; r < 4; ++r) s[qt][ct][r] += ma[r];
            }
        }

        // V fragments (independent of softmax; compiler overlaps)
        bf16x8 vf[2][4];
#pragma unroll
        for (int ks = 0; ks < 2; ++ks)
#pragma unroll
            for (int dt = 0; dt < 4; ++dt)
                vf[ks][dt] = *(const bf16x8*)&Vs[p][SW(dt * 16 + l16, ks * 32 + quad * 8)];

#pragma unroll
        for (int qt = 0; qt < 2; ++qt) {
            // p = exp2(s); per-lane partial l with explicit add tree
#pragma unroll
            for (int ct = 0; ct < 4; ++ct)
#pragma unroll
                for (int r = 0; r < 4; ++r)
                    s[qt][ct][r] = __builtin_amdgcn_exp2f(s[qt][ct][r]);
            float t0 = (s[qt][0][0] + s[qt][0][1]) + (s[qt][0][2] + s[qt][0][3]);
            float t1 = (s[qt][1][0] + s[qt][1][1]) + (s[qt][1][2] + s[qt][1][3]);
            float t2 = (s[qt][2][0] + s[qt][2][1]) + (s[qt][2][2] + s[qt][2][3]);
            float t3 = (s[qt][3][0] + s[qt][3][1]) + (s[qt][3][2] + s[qt][3][3]);
            l_i[qt] += (t0 + t1) + (t2 + t3);

            // pack to bf16 pairs: pk0[ct] = (r0,r1), pk1[ct] = (r2,r3)
            unsigned pk0[4], pk1[4];
#pragma unroll
            for (int ct = 0; ct < 4; ++ct) {
                asm("v_cvt_pk_bf16_f32 %0, %1, %2"
                    : "=v"(pk0[ct]) : "v"(s[qt][ct][0]), "v"(s[qt][ct][1]));
                asm("v_cvt_pk_bf16_f32 %0, %1, %2"
                    : "=v"(pk1[ct]) : "v"(s[qt][ct][2]), "v"(s[qt][ct][3]));
            }

#pragma unroll
            for (int ks = 0; ks < 2; ++ks) {
                unsigned a0 = pk0[2 * ks], c0 = pk0[2 * ks + 1];
                unsigned b0 = pk1[2 * ks], d0 = pk1[2 * ks + 1];
                asm("v_permlane32_swap_b32 %0, %1" : "+v"(a0), "+v"(c0));
                asm("v_permlane16_swap_b32 %0, %1" : "+v"(a0), "+v"(c0));
                asm("v_permlane32_swap_b32 %0, %1" : "+v"(b0), "+v"(d0));
                asm("v_permlane16_swap_b32 %0, %1" : "+v"(b0), "+v"(d0));
                union { unsigned u[4]; bf16x8 v; } ap;
                ap.u[0] = a0;  // j0,j1
                ap.u[1] = b0;  // j2,j3
                ap.u[2] = c0;  // j4,j5
                ap.u[3] = d0;  // j6,j7
#pragma unroll
                for (int dt = 0; dt < 4; ++dt)
                    o[qt][dt] = MFMA16(ap.v, vf[ks][dt], o[qt][dt]);
            }
        }

        // T14 write-late: staged tile -> other LDS buffer after compute
        if (pref) {
#pragma unroll
            for (int i = 0; i < 2; ++i) {
                int row = srow + i * 32;
                *(bf16x8*)&Ks[1 - p][SW(row, sc8)] = kreg[i];
                *(bf16x8*)&Vs[1 - p][SW(row, sc8)] = vreg[i];
            }
        }
        __syncthreads();
        p ^= 1;
    }

    // epilogue: cross-quad l reduce (out of the loop), then stores
    int h = bh % 12;
    bf16* obase = split ? po1 : po0;
#pragma unroll
    for (int qt = 0; qt < 2; ++qt) {
        l_i[qt] += __shfl_xor(l_i[qt], 16);
        l_i[qt] += __shfl_xor(l_i[qt], 32);
#pragma unroll
        for (int dt = 0; dt < 4; ++dt)
#pragma unroll
            for (int r = 0; r < 4; ++r) {
                int qrow = q0 + qt * 16 + quad * 4 + r;
                obase[((size_t)b * 2048 + qrow) * 768 + h * 64 + dt * 16 + l16] =
                    (bf16)o[qt][dt][r];
            }
        if (quad == 0) {
            int qrow = q0 + qt * 16 + l16;
            lbuf[((size_t)split * 24 + bh) * 2048 + qrow] = l_i[qt];
        }
    }
}

// ---------------------------------------------------------------------------
extern "C" void kernel_launch(void* const* d_in, const int* in_sizes, int n_in,
                              void* d_out, int out_size, void* d_ws, size_t ws_size,
                              hipStream_t stream) {
    float* out = (float*)d_out;

    const float* x = nullptr; const int* mask = nullptr;
    const float* w_qkv = nullptr; const float* b_qkv = nullptr;
    const float* w_out = nullptr; const float* b_out = nullptr;
    int found = 0;
    for (int i = 0; i < n_in; ++i) {
        switch (in_sizes[i]) {
            case 3145728: x     = (const float*)d_in[i]; found |= 1;  break;
            case 4096:    mask  = (const int*)  d_in[i]; found |= 2;  break;
            case 1769472: w_qkv = (const float*)d_in[i]; found |= 4;  break;
            case 2304:    b_qkv = (const float*)d_in[i]; found |= 8;  break;
            case 589824:  w_out = (const float*)d_in[i]; found |= 16; break;
            case 768:     b_out = (const float*)d_in[i]; found |= 32; break;
        }
    }
    if (found != 63) {
        mark_k<<<(out_size + 255) / 256, 256, 0, stream>>>(
            out, 200.0f + (float)found, out_size);
        return;
    }

    const int M = 4096, D = 768, N3 = 2304;
    const size_t HEADS_ELEMS = (size_t)24 * 2048 * 64;

    bf16* ws    = (bf16*)d_ws;
    bf16* Kh    = ws;
    bf16* Vth   = Kh + HEADS_ELEMS;
    bf16* po0   = Vth + HEADS_ELEMS;            // split-0 partial
    bf16* wqkvT = po0 + (size_t)M * D;
    bf16* woutT = wqkvT + (size_t)N3 * D;
    bf16* po1   = woutT + (size_t)D * D;        // split-1 partial
    bf16* Qh    = (bf16*)d_out;
    bf16* xb    = (bf16*)d_out + HEADS_ELEMS;   // dead after QKV
    float* lbuf = (float*)wqkvT;                // dead after QKV (393 KB)

    prep_k<<<dim3(1536 + 1728 + 576), 256, 0, stream>>>(
        x, xb, w_qkv, wqkvT, w_out, woutT);

    gemm_qkv_v6<<<dim3(576), 256, 0, stream>>>(
        xb, wqkvT, b_qkv, Qh, Kh, Vth);

    flash_attn<<<dim3(768), 256, 0, stream>>>(
        Qh, Kh, Vth, mask, po0, po1, lbuf);

    gemm_out_v6<<<dim3(384), 256, 0, stream>>>(
        po0, po1, lbuf, woutT, b_out, out);
}